// Round 5
// baseline (184.002 us; speedup 1.0000x reference)
//
#include <hip/hip_runtime.h>

// ---------------------------------------------------------------------------
// CNN + FC + 2x GraphSAGE, collapsed to scalar fields (GNN part is linear):
//   sa=a.h5, sr1=r1.h5, sc=c.h5, sr2=r2.h5 per (n,b)
//   W = mean1(sa)+sc ; out = mean2(W) + kb1*[deg>0] + mean1(sr1) + sr2 + kb2 + bl2
// Aggregation via per-call CSR + register-accumulating gather (NO f32 atomics).
// k_mlp: global->LDS staged (global_load_lds width 16, coalesced), one wave
// per (4 nodes x 16 batches); lane reads its own row from LDS.
// ---------------------------------------------------------------------------

__global__ void k_zero(int* __restrict__ cnt, int N) {
  int n = blockIdx.x * blockDim.x + threadIdx.x;
  if (n < N) cnt[n] = 0;
}

__global__ void k_count(const int* __restrict__ dst, int E, int* __restrict__ cnt) {
  int e = blockIdx.x * blockDim.x + threadIdx.x;
  if (e < E) atomicAdd(&cnt[dst[e]], 1);
}

// single block: exclusive scan cnt[N] -> row_ptr[N+1], plus cursor copy
__global__ __launch_bounds__(1024) void k_scan(const int* __restrict__ cnt, int N,
                                               int* __restrict__ row_ptr,
                                               int* __restrict__ cursor) {
  __shared__ int part[1024];
  int t = threadIdx.x;
  int chunk = (N + 1023) / 1024;
  int s0 = t * chunk, s1 = min(N, s0 + chunk);
  int sum = 0;
  for (int i = s0; i < s1; ++i) sum += cnt[i];
  part[t] = sum;
  __syncthreads();
  for (int off = 1; off < 1024; off <<= 1) {
    int v = (t >= off) ? part[t - off] : 0;
    __syncthreads();
    part[t] += v;
    __syncthreads();
  }
  int run = (t == 0) ? 0 : part[t - 1];
  for (int i = s0; i < s1; ++i) {
    row_ptr[i] = run; cursor[i] = run;
    run += cnt[i];
  }
  if (s1 == N) row_ptr[N] = run;
}

__global__ void k_scatter(const int* __restrict__ src, const int* __restrict__ dst, int E,
                          int* __restrict__ cursor, int* __restrict__ adj) {
  int e = blockIdx.x * blockDim.x + threadIdx.x;
  if (e < E) {
    int pos = atomicAdd(&cursor[dst[e]], 1);
    adj[pos] = src[e];
  }
}

// One wave per block. Block handles nodes [n0, n0+4) x all 16 batches = 64 rows.
// Stage: 1728 float4 chunks, instruction i DMAs chunk (i*64+lane) -> LDS linear.
// Compute: lane l owns LDS row l = (b = l&15, dn = l>>4).
__global__ __launch_bounds__(64) void k_mlp(
    const float* __restrict__ x,
    const float* __restrict__ w_t, const float* __restrict__ b_t,
    const float* __restrict__ w_r, const float* __restrict__ b_r,
    const float* __restrict__ w_tp, const float* __restrict__ b_tp,
    const float* __restrict__ w_ssr, const float* __restrict__ b_ssr,
    const float* __restrict__ f1w, const float* __restrict__ f1b,
    const float* __restrict__ f2w, const float* __restrict__ f2b,
    const float* __restrict__ g1_wl, const float* __restrict__ g1_wr,
    const float* __restrict__ g2_wl, const float* __restrict__ g2_wr,
    float2* __restrict__ F1v, float2* __restrict__ F2v, int N) {
  __shared__ float smem[64 * 108];  // 27648 B, linear (global_load_lds dest)
  const int l = threadIdx.x;
  const int n0 = blockIdx.x * 4;

#pragma unroll
  for (int i = 0; i < 27; ++i) {
    int ci = i * 64 + l;
    int slot = ci / 27;             // row 0..63
    int part = ci - slot * 27;      // float4 index within row
    int b = slot & 15, dn = slot >> 4;
    int nn = n0 + dn; if (nn >= N) nn = N - 1;
    const float* src = x + ((size_t)b * N + nn) * 108 + part * 4;
    __builtin_amdgcn_global_load_lds(
        (const __attribute__((address_space(1))) unsigned int*)src,
        (__attribute__((address_space(3))) unsigned int*)(smem + i * 256),
        16, 0, 0);
  }
  asm volatile("s_waitcnt vmcnt(0)" ::: "memory");
  __builtin_amdgcn_sched_barrier(0);

  const float* row = smem + l * 108;

  float feat[32];
#pragma unroll
  for (int i = 0; i < 3; ++i) {
    float4 v = *reinterpret_cast<const float4*>(row + 4 * i);
    feat[4 * i + 0] = v.x; feat[4 * i + 1] = v.y;
    feat[4 * i + 2] = v.z; feat[4 * i + 3] = v.w;
  }
  const float* cw[4] = {w_t, w_r, w_tp, w_ssr};
  const float* cb[4] = {b_t, b_r, b_tp, b_ssr};
#pragma unroll
  for (int br = 0; br < 4; ++br) {
    float acc[5];
#pragma unroll
    for (int o = 0; o < 5; ++o) acc[o] = cb[br][o];
#pragma unroll
    for (int q = 0; q < 6; ++q) {
      float4 w4 = *reinterpret_cast<const float4*>(row + 12 + br * 24 + 4 * q);
#pragma unroll
      for (int o = 0; o < 5; ++o) {
        acc[o] = fmaf(w4.x, cw[br][o * 24 + 4 * q + 0], acc[o]);
        acc[o] = fmaf(w4.y, cw[br][o * 24 + 4 * q + 1], acc[o]);
        acc[o] = fmaf(w4.z, cw[br][o * 24 + 4 * q + 2], acc[o]);
        acc[o] = fmaf(w4.w, cw[br][o * 24 + 4 * q + 3], acc[o]);
      }
    }
#pragma unroll
    for (int o = 0; o < 5; ++o) feat[12 + br * 5 + o] = fmaxf(acc[o], 0.f);
  }

  float h20[20];
#pragma unroll
  for (int o = 0; o < 20; ++o) {
    float acc = f1b[o];
#pragma unroll
    for (int i = 0; i < 32; ++i) acc = fmaf(feat[i], f1w[o * 32 + i], acc);
    h20[o] = fmaxf(acc, 0.f);
  }
  float h5[5];
#pragma unroll
  for (int o = 0; o < 5; ++o) {
    float acc = f2b[o];
#pragma unroll
    for (int i = 0; i < 20; ++i) acc = fmaf(h20[i], f2w[o * 20 + i], acc);
    h5[o] = acc;
  }

  float sa = 0.f, sr1 = 0.f, sc = 0.f, sr2 = 0.f;
#pragma unroll
  for (int j = 0; j < 20; ++j) {
    float t1 = 0.f, t2 = 0.f;
#pragma unroll
    for (int k = 0; k < 5; ++k) {
      t1 = fmaf(g1_wl[j * 5 + k], h5[k], t1);
      t2 = fmaf(g1_wr[j * 5 + k], h5[k], t2);
    }
    float wl2 = g2_wl[j], wr2 = g2_wr[j];
    sa  = fmaf(wl2, t1, sa);
    sr1 = fmaf(wr2, t1, sr1);
    sc  = fmaf(wl2, t2, sc);
    sr2 = fmaf(wr2, t2, sr2);
  }

  // lane l -> (b=l&15, dn=l>>4) -> F index (n0+dn)*16+b = n0*16 + l : coalesced
  if (n0 + (l >> 4) < N) {
    size_t o = (size_t)n0 * 16 + l;
    F1v[o] = make_float2(sa, sr1);
    F2v[o] = make_float2(sc, sr2);
  }
}

// 16 lanes per node (one per batch). Adjacency: coalesced 16-chunk load +
// __shfl broadcast. Gather F1v[s*16+b] = 128B contiguous per group.
__global__ void k_agg1(const int* __restrict__ row_ptr, const int* __restrict__ adj,
                       const float2* __restrict__ F1v, const float2* __restrict__ F2v,
                       float* __restrict__ W, float* __restrict__ V, int N) {
  int t = blockIdx.x * blockDim.x + threadIdx.x;
  int g = t >> 4, b = t & 15;
  if (g >= N) return;
  int beg = row_ptr[g], end = row_ptr[g + 1];
  float sa = 0.f, sb = 0.f;
  for (int c = beg; c < end; c += 16) {
    int idx = c + b;
    int a = adj[idx < end ? idx : end - 1];
    int m = min(16, end - c);
#pragma unroll 4
    for (int k = 0; k < m; ++k) {
      int s = __shfl(a, k, 16);
      float2 f = F1v[s * 16 + b];
      sa += f.x; sb += f.y;
    }
  }
  float inv = 1.0f / fmaxf((float)(end - beg), 1.0f);
  float2 f2 = F2v[t];
  W[t] = sa * inv + f2.x;
  V[t] = sb * inv;
}

// second gather over W, fused with the final epilogue; LDS transpose so the
// out[b*N+n] write is coalesced per plane.
__global__ __launch_bounds__(256) void k_agg2(
    const int* __restrict__ row_ptr, const int* __restrict__ adj,
    const float* __restrict__ W, const float* __restrict__ V,
    const float2* __restrict__ F2v,
    const float* __restrict__ g1_bl, const float* __restrict__ g2_wl,
    const float* __restrict__ g2_wr, const float* __restrict__ g2_bl,
    float* __restrict__ out, int N) {
  __shared__ float tile[16][17];
  int t = blockIdx.x * 256 + threadIdx.x;
  int g = t >> 4, b = t & 15;
  float r = 0.f;
  if (g < N) {
    int beg = row_ptr[g], end = row_ptr[g + 1];
    float sw = 0.f;
    for (int c = beg; c < end; c += 16) {
      int idx = c + b;
      int a = adj[idx < end ? idx : end - 1];
      int m = min(16, end - c);
#pragma unroll 4
      for (int k = 0; k < m; ++k) {
        int s = __shfl(a, k, 16);
        sw += W[s * 16 + b];
      }
    }
    float kb1 = 0.f, kb2 = 0.f;
#pragma unroll
    for (int j = 0; j < 20; ++j) {
      kb1 = fmaf(g2_wl[j], g1_bl[j], kb1);
      kb2 = fmaf(g2_wr[j], g1_bl[j], kb2);
    }
    int deg = end - beg;
    float inv = 1.0f / fmaxf((float)deg, 1.0f);
    float chi = deg > 0 ? 1.f : 0.f;
    r = sw * inv + V[t] + F2v[t].y + kb1 * chi + kb2 + g2_bl[0];
  }
  int gl = (threadIdx.x >> 4);
  tile[b][gl] = r;
  __syncthreads();
  int b2 = threadIdx.x >> 4;
  int gl2 = threadIdx.x & 15;
  int n2 = blockIdx.x * 16 + gl2;
  if (n2 < N) out[(size_t)b2 * N + n2] = tile[b2][gl2];
}

extern "C" void kernel_launch(void* const* d_in, const int* in_sizes, int n_in,
                              void* d_out, int out_size, void* d_ws, size_t ws_size,
                              hipStream_t stream) {
  const float* x     = (const float*)d_in[0];
  const int*   ei    = (const int*)d_in[1];
  const float* w_t   = (const float*)d_in[2];
  const float* b_t   = (const float*)d_in[3];
  const float* w_r   = (const float*)d_in[4];
  const float* b_r   = (const float*)d_in[5];
  const float* w_tp  = (const float*)d_in[6];
  const float* b_tp  = (const float*)d_in[7];
  const float* w_ssr = (const float*)d_in[8];
  const float* b_ssr = (const float*)d_in[9];
  const float* f1w   = (const float*)d_in[10];
  const float* f1b   = (const float*)d_in[11];
  const float* f2w   = (const float*)d_in[12];
  const float* f2b   = (const float*)d_in[13];
  const float* g1_wl = (const float*)d_in[14];
  const float* g1_bl = (const float*)d_in[15];
  const float* g1_wr = (const float*)d_in[16];
  const float* g2_wl = (const float*)d_in[17];
  const float* g2_bl = (const float*)d_in[18];
  const float* g2_wr = (const float*)d_in[19];
  float* out = (float*)d_out;

  const int E = in_sizes[1] / 2;
  const int N = out_size / 16;   // B = 16
  const int* src = ei;
  const int* dst = ei + E;

  // workspace
  float* ws  = (float*)d_ws;
  float2* F1v = (float2*)ws;                    // 16N float2
  float2* F2v = F1v + (size_t)16 * N;           // 16N float2
  float*  W   = (float*)(F2v + (size_t)16 * N); // 16N f32
  float*  V   = W + (size_t)16 * N;             // 16N f32
  int* cnt     = (int*)(V + (size_t)16 * N);    // N
  int* row_ptr = cnt + N;                       // N+1
  int* cursor  = row_ptr + N + 1;               // N
  int* adj     = cursor + N;                    // E

  int nb16 = (N * 16 + 255) / 256;
  int nmlp = (N + 3) / 4;                       // 1-wave blocks, 4 nodes each

  k_zero<<<(N + 255) / 256, 256, 0, stream>>>(cnt, N);
  k_count<<<(E + 255) / 256, 256, 0, stream>>>(dst, E, cnt);
  k_scan<<<1, 1024, 0, stream>>>(cnt, N, row_ptr, cursor);
  k_scatter<<<(E + 255) / 256, 256, 0, stream>>>(src, dst, E, cursor, adj);
  k_mlp<<<nmlp, 64, 0, stream>>>(
      x, w_t, b_t, w_r, b_r, w_tp, b_tp, w_ssr, b_ssr,
      f1w, f1b, f2w, f2b, g1_wl, g1_wr, g2_wl, g2_wr, F1v, F2v, N);
  k_agg1<<<nb16, 256, 0, stream>>>(row_ptr, adj, F1v, F2v, W, V, N);
  k_agg2<<<nb16, 256, 0, stream>>>(row_ptr, adj, W, V, F2v,
                                   g1_bl, g2_wl, g2_wr, g2_bl, out, N);
}

// Round 6
// 148.579 us; speedup vs baseline: 1.2384x; 1.2384x over previous
//
#include <hip/hip_runtime.h>

// ---------------------------------------------------------------------------
// CNN + FC + 2x GraphSAGE, collapsed to scalar fields (GNN part is linear):
//   sa=a.h5, sr1=r1.h5, sc=c.h5, sr2=r2.h5 per (n,b)
//   W = mean1(sa)+sc ; out = mean2(W) + kb1*[deg>0] + mean1(sr1) + sr2 + kb2 + bl2
// Aggregation via per-call CSR + register-accumulating gather (NO f32 atomics).
// k_mlp: one row per thread; all 27 float4 row-loads pinned in registers via
// empty asm volatile (compiler cannot sink them) -> ~27 loads in flight/wave.
// ---------------------------------------------------------------------------

__global__ void k_zero(int* __restrict__ cnt, int N) {
  int n = blockIdx.x * blockDim.x + threadIdx.x;
  if (n < N) cnt[n] = 0;
}

__global__ void k_count(const int* __restrict__ dst, int E, int* __restrict__ cnt) {
  int e = blockIdx.x * blockDim.x + threadIdx.x;
  if (e < E) atomicAdd(&cnt[dst[e]], 1);
}

// single block: exclusive scan cnt[N] -> row_ptr[N+1], plus cursor copy
__global__ __launch_bounds__(1024) void k_scan(const int* __restrict__ cnt, int N,
                                               int* __restrict__ row_ptr,
                                               int* __restrict__ cursor) {
  __shared__ int part[1024];
  int t = threadIdx.x;
  int chunk = (N + 1023) / 1024;
  int s0 = t * chunk, s1 = min(N, s0 + chunk);
  int sum = 0;
  for (int i = s0; i < s1; ++i) sum += cnt[i];
  part[t] = sum;
  __syncthreads();
  for (int off = 1; off < 1024; off <<= 1) {
    int v = (t >= off) ? part[t - off] : 0;
    __syncthreads();
    part[t] += v;
    __syncthreads();
  }
  int run = (t == 0) ? 0 : part[t - 1];
  for (int i = s0; i < s1; ++i) {
    row_ptr[i] = run; cursor[i] = run;
    run += cnt[i];
  }
  if (s1 == N) row_ptr[N] = run;
}

__global__ void k_scatter(const int* __restrict__ src, const int* __restrict__ dst, int E,
                          int* __restrict__ cursor, int* __restrict__ adj) {
  int e = blockIdx.x * blockDim.x + threadIdx.x;
  if (e < E) {
    int pos = atomicAdd(&cursor[dst[e]], 1);
    adj[pos] = src[e];
  }
}

// One row (b,n) per thread, rr = b*N + n (x memory order).
__global__ __launch_bounds__(256) void k_mlp(
    const float* __restrict__ x,
    const float* __restrict__ w_t, const float* __restrict__ b_t,
    const float* __restrict__ w_r, const float* __restrict__ b_r,
    const float* __restrict__ w_tp, const float* __restrict__ b_tp,
    const float* __restrict__ w_ssr, const float* __restrict__ b_ssr,
    const float* __restrict__ f1w, const float* __restrict__ f1b,
    const float* __restrict__ f2w, const float* __restrict__ f2b,
    const float* __restrict__ g1_wl, const float* __restrict__ g1_wr,
    const float* __restrict__ g2_wl, const float* __restrict__ g2_wr,
    float2* __restrict__ F1v, float2* __restrict__ F2v, int N, int rows) {
  int rr = blockIdx.x * 256 + threadIdx.x;
  if (rr >= rows) return;

  // Load the full 432B row. The empty volatile asms pin every component in a
  // VGPR at this point, so the compiler must issue ALL 27 loads before any
  // compute (it cannot sink or rematerialize them). ~27 loads in flight/wave.
  const float4* xv = reinterpret_cast<const float4*>(x + (size_t)rr * 108);
  float4 v[27];
#pragma unroll
  for (int i = 0; i < 27; ++i) v[i] = xv[i];
#pragma unroll
  for (int i = 0; i < 27; ++i)
    asm volatile("" : "+v"(v[i].x), "+v"(v[i].y), "+v"(v[i].z), "+v"(v[i].w));
  __builtin_amdgcn_sched_barrier(0);

  float feat[32];
#pragma unroll
  for (int i = 0; i < 3; ++i) {
    feat[4 * i + 0] = v[i].x; feat[4 * i + 1] = v[i].y;
    feat[4 * i + 2] = v[i].z; feat[4 * i + 3] = v[i].w;
  }
  const float* cw[4] = {w_t, w_r, w_tp, w_ssr};
  const float* cb[4] = {b_t, b_r, b_tp, b_ssr};
#pragma unroll
  for (int br = 0; br < 4; ++br) {
    float acc[5];
#pragma unroll
    for (int o = 0; o < 5; ++o) acc[o] = cb[br][o];
#pragma unroll
    for (int q = 0; q < 6; ++q) {
      float4 w4 = v[3 + 6 * br + q];
#pragma unroll
      for (int o = 0; o < 5; ++o) {
        acc[o] = fmaf(w4.x, cw[br][o * 24 + 4 * q + 0], acc[o]);
        acc[o] = fmaf(w4.y, cw[br][o * 24 + 4 * q + 1], acc[o]);
        acc[o] = fmaf(w4.z, cw[br][o * 24 + 4 * q + 2], acc[o]);
        acc[o] = fmaf(w4.w, cw[br][o * 24 + 4 * q + 3], acc[o]);
      }
    }
#pragma unroll
    for (int o = 0; o < 5; ++o) feat[12 + br * 5 + o] = fmaxf(acc[o], 0.f);
  }

  float h20[20];
#pragma unroll
  for (int o = 0; o < 20; ++o) {
    float acc = f1b[o];
#pragma unroll
    for (int i = 0; i < 32; ++i) acc = fmaf(feat[i], f1w[o * 32 + i], acc);
    h20[o] = fmaxf(acc, 0.f);
  }
  float h5[5];
#pragma unroll
  for (int o = 0; o < 5; ++o) {
    float acc = f2b[o];
#pragma unroll
    for (int i = 0; i < 20; ++i) acc = fmaf(h20[i], f2w[o * 20 + i], acc);
    h5[o] = acc;
  }

  float sa = 0.f, sr1 = 0.f, sc = 0.f, sr2 = 0.f;
#pragma unroll
  for (int j = 0; j < 20; ++j) {
    float t1 = 0.f, t2 = 0.f;
#pragma unroll
    for (int k = 0; k < 5; ++k) {
      t1 = fmaf(g1_wl[j * 5 + k], h5[k], t1);
      t2 = fmaf(g1_wr[j * 5 + k], h5[k], t2);
    }
    float wl2 = g2_wl[j], wr2 = g2_wr[j];
    sa  = fmaf(wl2, t1, sa);
    sr1 = fmaf(wr2, t1, sr1);
    sc  = fmaf(wl2, t2, sc);
    sr2 = fmaf(wr2, t2, sr2);
  }

  int b = rr / N;
  int n = rr - b * N;
  F1v[n * 16 + b] = make_float2(sa, sr1);
  F2v[n * 16 + b] = make_float2(sc, sr2);
}

// 16 lanes per node (one per batch). Adjacency: coalesced 16-chunk load +
// __shfl broadcast. Gather F1v[s*16+b] = 128B contiguous per group.
__global__ void k_agg1(const int* __restrict__ row_ptr, const int* __restrict__ adj,
                       const float2* __restrict__ F1v, const float2* __restrict__ F2v,
                       float* __restrict__ W, float* __restrict__ V, int N) {
  int t = blockIdx.x * blockDim.x + threadIdx.x;
  int g = t >> 4, b = t & 15;
  if (g >= N) return;
  int beg = row_ptr[g], end = row_ptr[g + 1];
  float sa = 0.f, sb = 0.f;
  for (int c = beg; c < end; c += 16) {
    int idx = c + b;
    int a = adj[idx < end ? idx : end - 1];
    int m = min(16, end - c);
#pragma unroll 4
    for (int k = 0; k < m; ++k) {
      int s = __shfl(a, k, 16);
      float2 f = F1v[s * 16 + b];
      sa += f.x; sb += f.y;
    }
  }
  float inv = 1.0f / fmaxf((float)(end - beg), 1.0f);
  float2 f2 = F2v[t];
  W[t] = sa * inv + f2.x;
  V[t] = sb * inv;
}

// second gather over W, fused with the final epilogue; LDS transpose so the
// out[b*N+n] write is coalesced per plane.
__global__ __launch_bounds__(256) void k_agg2(
    const int* __restrict__ row_ptr, const int* __restrict__ adj,
    const float* __restrict__ W, const float* __restrict__ V,
    const float2* __restrict__ F2v,
    const float* __restrict__ g1_bl, const float* __restrict__ g2_wl,
    const float* __restrict__ g2_wr, const float* __restrict__ g2_bl,
    float* __restrict__ out, int N) {
  __shared__ float tile[16][17];
  int t = blockIdx.x * 256 + threadIdx.x;
  int g = t >> 4, b = t & 15;
  float r = 0.f;
  if (g < N) {
    int beg = row_ptr[g], end = row_ptr[g + 1];
    float sw = 0.f;
    for (int c = beg; c < end; c += 16) {
      int idx = c + b;
      int a = adj[idx < end ? idx : end - 1];
      int m = min(16, end - c);
#pragma unroll 4
      for (int k = 0; k < m; ++k) {
        int s = __shfl(a, k, 16);
        sw += W[s * 16 + b];
      }
    }
    float kb1 = 0.f, kb2 = 0.f;
#pragma unroll
    for (int j = 0; j < 20; ++j) {
      kb1 = fmaf(g2_wl[j], g1_bl[j], kb1);
      kb2 = fmaf(g2_wr[j], g1_bl[j], kb2);
    }
    int deg = end - beg;
    float inv = 1.0f / fmaxf((float)deg, 1.0f);
    float chi = deg > 0 ? 1.f : 0.f;
    r = sw * inv + V[t] + F2v[t].y + kb1 * chi + kb2 + g2_bl[0];
  }
  int gl = (threadIdx.x >> 4);
  tile[b][gl] = r;
  __syncthreads();
  int b2 = threadIdx.x >> 4;
  int gl2 = threadIdx.x & 15;
  int n2 = blockIdx.x * 16 + gl2;
  if (n2 < N) out[(size_t)b2 * N + n2] = tile[b2][gl2];
}

extern "C" void kernel_launch(void* const* d_in, const int* in_sizes, int n_in,
                              void* d_out, int out_size, void* d_ws, size_t ws_size,
                              hipStream_t stream) {
  const float* x     = (const float*)d_in[0];
  const int*   ei    = (const int*)d_in[1];
  const float* w_t   = (const float*)d_in[2];
  const float* b_t   = (const float*)d_in[3];
  const float* w_r   = (const float*)d_in[4];
  const float* b_r   = (const float*)d_in[5];
  const float* w_tp  = (const float*)d_in[6];
  const float* b_tp  = (const float*)d_in[7];
  const float* w_ssr = (const float*)d_in[8];
  const float* b_ssr = (const float*)d_in[9];
  const float* f1w   = (const float*)d_in[10];
  const float* f1b   = (const float*)d_in[11];
  const float* f2w   = (const float*)d_in[12];
  const float* f2b   = (const float*)d_in[13];
  const float* g1_wl = (const float*)d_in[14];
  const float* g1_bl = (const float*)d_in[15];
  const float* g1_wr = (const float*)d_in[16];
  const float* g2_wl = (const float*)d_in[17];
  const float* g2_bl = (const float*)d_in[18];
  const float* g2_wr = (const float*)d_in[19];
  float* out = (float*)d_out;

  const int E = in_sizes[1] / 2;
  const int N = out_size / 16;   // B = 16
  const int rows = out_size;     // N * B
  const int* src = ei;
  const int* dst = ei + E;

  // workspace
  float* ws  = (float*)d_ws;
  float2* F1v = (float2*)ws;                    // 16N float2
  float2* F2v = F1v + (size_t)16 * N;           // 16N float2
  float*  W   = (float*)(F2v + (size_t)16 * N); // 16N f32
  float*  V   = W + (size_t)16 * N;             // 16N f32
  int* cnt     = (int*)(V + (size_t)16 * N);    // N
  int* row_ptr = cnt + N;                       // N+1
  int* cursor  = row_ptr + N + 1;               // N
  int* adj     = cursor + N;                    // E

  int nb16 = (N * 16 + 255) / 256;

  k_zero<<<(N + 255) / 256, 256, 0, stream>>>(cnt, N);
  k_count<<<(E + 255) / 256, 256, 0, stream>>>(dst, E, cnt);
  k_scan<<<1, 1024, 0, stream>>>(cnt, N, row_ptr, cursor);
  k_scatter<<<(E + 255) / 256, 256, 0, stream>>>(src, dst, E, cursor, adj);
  k_mlp<<<(rows + 255) / 256, 256, 0, stream>>>(
      x, w_t, b_t, w_r, b_r, w_tp, b_tp, w_ssr, b_ssr,
      f1w, f1b, f2w, f2b, g1_wl, g1_wr, g2_wl, g2_wr, F1v, F2v, N, rows);
  k_agg1<<<nb16, 256, 0, stream>>>(row_ptr, adj, F1v, F2v, W, V, N);
  k_agg2<<<nb16, 256, 0, stream>>>(row_ptr, adj, W, V, F2v,
                                   g1_bl, g2_wl, g2_wr, g2_bl, out, N);
}

// Round 8
// 145.496 us; speedup vs baseline: 1.2647x; 1.0212x over previous
//
#include <hip/hip_runtime.h>

// ---------------------------------------------------------------------------
// CNN + FC + 2x GraphSAGE, collapsed to scalar fields (GNN part is linear).
// fc2 + both SAGE layers folded into 86 coefficients (computed in k_scan):
//   s_f = coef[80+f] + sum_i h20[i]*coef[f*20+i],  f in {sa,sr1,sc,sr2}
//   W = mean1(sa)+sc ; out = mean2(W) + kb1*[deg>0] + mean1(sr1) + sr2 + kb2 + bl2
// k_mlp: 4 threads per row (one conv branch each, 6-7 float4 loads/thread),
// feat/h20 exchanged via padded LDS; ALL weights staged to LDS per block.
// Aggregation via per-call CSR + register-accumulating gather (no f32 atomics).
// ---------------------------------------------------------------------------

#define F1W 500
#define F1B 1160
#define CO  1180
#define FEAT 1266
#define HL   3378
// total LDS floats: 3378 + 64*25 = 4978 (~19.9 KB)

__global__ void k_zero(int* __restrict__ cnt, int N) {
  int n = blockIdx.x * blockDim.x + threadIdx.x;
  if (n < N) cnt[n] = 0;
}

__global__ void k_count(const int* __restrict__ dst, int E, int* __restrict__ cnt) {
  int e = blockIdx.x * blockDim.x + threadIdx.x;
  if (e < E) atomicAdd(&cnt[dst[e]], 1);
}

// single block: weight folding (threads 0..20) + exclusive scan of cnt
__global__ __launch_bounds__(1024) void k_scan(
    const int* __restrict__ cnt, int N,
    int* __restrict__ row_ptr, int* __restrict__ cursor,
    const float* __restrict__ f2w, const float* __restrict__ f2b,
    const float* __restrict__ g1_wl, const float* __restrict__ g1_bl,
    const float* __restrict__ g1_wr, const float* __restrict__ g2_wl,
    const float* __restrict__ g2_wr, float* __restrict__ coef) {
  int t = threadIdx.x;

  if (t < 21) {
    float a[5], r1[5], c[5], r2[5];
#pragma unroll
    for (int k = 0; k < 5; ++k) { a[k] = 0.f; r1[k] = 0.f; c[k] = 0.f; r2[k] = 0.f; }
#pragma unroll
    for (int j = 0; j < 20; ++j) {
      float wl2 = g2_wl[j], wr2 = g2_wr[j];
#pragma unroll
      for (int k = 0; k < 5; ++k) {
        float wl1 = g1_wl[j * 5 + k], wr1 = g1_wr[j * 5 + k];
        a[k]  = fmaf(wl2, wl1, a[k]);
        r1[k] = fmaf(wr2, wl1, r1[k]);
        c[k]  = fmaf(wl2, wr1, c[k]);
        r2[k] = fmaf(wr2, wr1, r2[k]);
      }
    }
    if (t < 20) {
      float A = 0.f, R1 = 0.f, C = 0.f, R2 = 0.f;
#pragma unroll
      for (int k = 0; k < 5; ++k) {
        float w = f2w[k * 20 + t];
        A  = fmaf(a[k],  w, A);
        R1 = fmaf(r1[k], w, R1);
        C  = fmaf(c[k],  w, C);
        R2 = fmaf(r2[k], w, R2);
      }
      coef[t] = A; coef[20 + t] = R1; coef[40 + t] = C; coef[60 + t] = R2;
    } else {
      float ca = 0.f, cr1 = 0.f, cc = 0.f, cr2 = 0.f;
#pragma unroll
      for (int k = 0; k < 5; ++k) {
        float b = f2b[k];
        ca = fmaf(a[k], b, ca);  cr1 = fmaf(r1[k], b, cr1);
        cc = fmaf(c[k], b, cc);  cr2 = fmaf(r2[k], b, cr2);
      }
      coef[80] = ca; coef[81] = cr1; coef[82] = cc; coef[83] = cr2;
      float kb1 = 0.f, kb2 = 0.f;
#pragma unroll
      for (int j = 0; j < 20; ++j) {
        kb1 = fmaf(g2_wl[j], g1_bl[j], kb1);
        kb2 = fmaf(g2_wr[j], g1_bl[j], kb2);
      }
      coef[84] = kb1; coef[85] = kb2;
    }
  }

  __shared__ int part[1024];
  int chunk = (N + 1023) / 1024;
  int s0 = t * chunk, s1 = min(N, s0 + chunk);
  int sum = 0;
  for (int i = s0; i < s1; ++i) sum += cnt[i];
  part[t] = sum;
  __syncthreads();
  for (int off = 1; off < 1024; off <<= 1) {
    int v = (t >= off) ? part[t - off] : 0;
    __syncthreads();
    part[t] += v;
    __syncthreads();
  }
  int run = (t == 0) ? 0 : part[t - 1];
  for (int i = s0; i < s1; ++i) {
    row_ptr[i] = run; cursor[i] = run;
    run += cnt[i];
  }
  if (s1 == N) row_ptr[N] = run;
}

__global__ void k_scatter(const int* __restrict__ src, const int* __restrict__ dst, int E,
                          int* __restrict__ cursor, int* __restrict__ adj) {
  int e = blockIdx.x * blockDim.x + threadIdx.x;
  if (e < E) {
    int pos = atomicAdd(&cursor[dst[e]], 1);
    adj[pos] = src[e];
  }
}

// 4 threads per row: q = t&3 owns conv branch q (chunks 3+6q .. 8+6q) and,
// for q>0, passthrough chunk q-1. feat/h20 exchanged via padded LDS.
__global__ __launch_bounds__(256) void k_mlp(
    const float* __restrict__ x,
    const float* __restrict__ w_t, const float* __restrict__ b_t,
    const float* __restrict__ w_r, const float* __restrict__ b_r,
    const float* __restrict__ w_tp, const float* __restrict__ b_tp,
    const float* __restrict__ w_ssr, const float* __restrict__ b_ssr,
    const float* __restrict__ f1w, const float* __restrict__ f1b,
    const float* __restrict__ coef,
    float2* __restrict__ F1v, float2* __restrict__ F2v, int N, int rows) {
  __shared__ float S[4978];
  const int t = threadIdx.x;
  const int q = t & 3, r = t >> 2;
  int rr = blockIdx.x * 64 + r;
  bool live = rr < rows;
  if (!live) rr = rows - 1;

  // ---- issue this thread's x loads (6-7 float4, naturally grouped) ----
  const float4* xv = reinterpret_cast<const float4*>(x + (size_t)rr * 108);
  float4 bv[6];
#pragma unroll
  for (int i = 0; i < 6; ++i) bv[i] = xv[3 + 6 * q + i];
  float4 pv = make_float4(0.f, 0.f, 0.f, 0.f);
  if (q > 0) pv = xv[q - 1];

  // ---- stage all weights + coefs into LDS (overlaps the x loads) ----
  if (t < 120) {
    S[t] = w_t[t]; S[120 + t] = w_r[t]; S[240 + t] = w_tp[t]; S[360 + t] = w_ssr[t];
  }
  if (t < 5) {
    S[480 + t] = b_t[t]; S[485 + t] = b_r[t];
    S[490 + t] = b_tp[t]; S[495 + t] = b_ssr[t];
  }
  for (int i = t; i < 640; i += 256) {
    int o = i >> 5, k = i & 31;
    S[F1W + o * 33 + k] = f1w[i];      // padded stride 33: conflict-free fc1 reads
  }
  if (t < 20) S[F1B + t] = f1b[t];
  if (t >= 128 && t < 128 + 86) S[CO + t - 128] = coef[t - 128];
  __syncthreads();

  // ---- conv branch q (weights via LDS; 4 addrs/instr, distinct banks) ----
  float acc[5];
#pragma unroll
  for (int o = 0; o < 5; ++o) acc[o] = S[480 + q * 5 + o];
#pragma unroll
  for (int i = 0; i < 6; ++i) {
    float4 w4 = bv[i];
#pragma unroll
    for (int o = 0; o < 5; ++o) {
      const int wb = q * 120 + o * 24 + 4 * i;
      acc[o] = fmaf(w4.x, S[wb + 0], acc[o]);
      acc[o] = fmaf(w4.y, S[wb + 1], acc[o]);
      acc[o] = fmaf(w4.z, S[wb + 2], acc[o]);
      acc[o] = fmaf(w4.w, S[wb + 3], acc[o]);
    }
  }
  // feat exchange (row stride 33 -> banks spread across rows)
  float* fr = &S[FEAT + r * 33];
  if (q > 0) {
    fr[4 * (q - 1) + 0] = pv.x; fr[4 * (q - 1) + 1] = pv.y;
    fr[4 * (q - 1) + 2] = pv.z; fr[4 * (q - 1) + 3] = pv.w;
  }
#pragma unroll
  for (int o = 0; o < 5; ++o) fr[12 + q * 5 + o] = fmaxf(acc[o], 0.f);
  __syncthreads();

  // ---- fc1: thread computes outputs o = q*5 + j ----
  float a2[5];
#pragma unroll
  for (int j = 0; j < 5; ++j) a2[j] = S[F1B + q * 5 + j];
#pragma unroll
  for (int i = 0; i < 32; ++i) {
    float f = fr[i];
#pragma unroll
    for (int j = 0; j < 5; ++j)
      a2[j] = fmaf(f, S[F1W + (q * 5 + j) * 33 + i], a2[j]);
  }
  float* hr = &S[HL + r * 25];
#pragma unroll
  for (int j = 0; j < 5; ++j) hr[q * 5 + j] = fmaxf(a2[j], 0.f);
  __syncthreads();

  // ---- folded fc2+SAGE: thread computes scalar field f = q ----
  float s = S[CO + 80 + q];
#pragma unroll
  for (int i = 0; i < 20; ++i) s = fmaf(hr[i], S[CO + q * 20 + i], s);
  hr[20 + q] = s;
  __syncthreads();

  if (q == 0 && live) {
    int b = rr / N;
    int n = rr - b * N;
    F1v[n * 16 + b] = make_float2(hr[20], hr[21]);
    F2v[n * 16 + b] = make_float2(hr[22], hr[23]);
  }
}

// 16 lanes per node (one per batch). Adjacency: coalesced 16-chunk load +
// __shfl broadcast. Gather F1v[s*16+b] = 128B contiguous per group.
__global__ void k_agg1(const int* __restrict__ row_ptr, const int* __restrict__ adj,
                       const float2* __restrict__ F1v, const float2* __restrict__ F2v,
                       float* __restrict__ W, float* __restrict__ V, int N) {
  int t = blockIdx.x * blockDim.x + threadIdx.x;
  int g = t >> 4, b = t & 15;
  if (g >= N) return;
  int beg = row_ptr[g], end = row_ptr[g + 1];
  float sa = 0.f, sb = 0.f;
  for (int c = beg; c < end; c += 16) {
    int idx = c + b;
    int a = adj[idx < end ? idx : end - 1];
    int m = min(16, end - c);
    for (int k = 0; k < m; ++k) {
      int s = __shfl(a, k, 16);
      float2 f = F1v[s * 16 + b];
      sa += f.x; sb += f.y;
    }
  }
  float inv = 1.0f / fmaxf((float)(end - beg), 1.0f);
  float2 f2 = F2v[t];
  W[t] = sa * inv + f2.x;
  V[t] = sb * inv;
}

// second gather over W, fused with the final epilogue; LDS transpose so the
// out[b*N+n] write is coalesced per plane.
__global__ __launch_bounds__(256) void k_agg2(
    const int* __restrict__ row_ptr, const int* __restrict__ adj,
    const float* __restrict__ W, const float* __restrict__ V,
    const float2* __restrict__ F2v, const float* __restrict__ coef,
    const float* __restrict__ g2_bl, float* __restrict__ out, int N) {
  __shared__ float tile[16][17];
  int t = blockIdx.x * 256 + threadIdx.x;
  int g = t >> 4, b = t & 15;
  float r = 0.f;
  if (g < N) {
    int beg = row_ptr[g], end = row_ptr[g + 1];
    float sw = 0.f;
    for (int c = beg; c < end; c += 16) {
      int idx = c + b;
      int a = adj[idx < end ? idx : end - 1];
      int m = min(16, end - c);
      for (int k = 0; k < m; ++k) {
        int s = __shfl(a, k, 16);
        sw += W[s * 16 + b];
      }
    }
    int deg = end - beg;
    float inv = 1.0f / fmaxf((float)deg, 1.0f);
    float chi = deg > 0 ? 1.f : 0.f;
    r = sw * inv + V[t] + F2v[t].y + coef[84] * chi + coef[85] + g2_bl[0];
  }
  int gl = (threadIdx.x >> 4);
  tile[b][gl] = r;
  __syncthreads();
  int b2 = threadIdx.x >> 4;
  int gl2 = threadIdx.x & 15;
  int n2 = blockIdx.x * 16 + gl2;
  if (n2 < N) out[(size_t)b2 * N + n2] = tile[b2][gl2];
}

extern "C" void kernel_launch(void* const* d_in, const int* in_sizes, int n_in,
                              void* d_out, int out_size, void* d_ws, size_t ws_size,
                              hipStream_t stream) {
  const float* x     = (const float*)d_in[0];
  const int*   ei    = (const int*)d_in[1];
  const float* w_t   = (const float*)d_in[2];
  const float* b_t   = (const float*)d_in[3];
  const float* w_r   = (const float*)d_in[4];
  const float* b_r   = (const float*)d_in[5];
  const float* w_tp  = (const float*)d_in[6];
  const float* b_tp  = (const float*)d_in[7];
  const float* w_ssr = (const float*)d_in[8];
  const float* b_ssr = (const float*)d_in[9];
  const float* f1w   = (const float*)d_in[10];
  const float* f1b   = (const float*)d_in[11];
  const float* f2w   = (const float*)d_in[12];
  const float* f2b   = (const float*)d_in[13];
  const float* g1_wl = (const float*)d_in[14];
  const float* g1_bl = (const float*)d_in[15];
  const float* g1_wr = (const float*)d_in[16];
  const float* g2_wl = (const float*)d_in[17];
  const float* g2_bl = (const float*)d_in[18];
  const float* g2_wr = (const float*)d_in[19];
  float* out = (float*)d_out;

  const int E = in_sizes[1] / 2;
  const int N = out_size / 16;   // B = 16
  const int rows = out_size;     // N * B
  const int* src = ei;
  const int* dst = ei + E;

  // workspace
  float* ws  = (float*)d_ws;
  float2* F1v = (float2*)ws;                    // 16N float2
  float2* F2v = F1v + (size_t)16 * N;           // 16N float2
  float*  W   = (float*)(F2v + (size_t)16 * N); // 16N f32
  float*  V   = W + (size_t)16 * N;             // 16N f32
  float*  coef = V + (size_t)16 * N;            // 86
  int* cnt     = (int*)(coef + 128);            // N
  int* row_ptr = cnt + N;                       // N+1
  int* cursor  = row_ptr + N + 1;               // N
  int* adj     = cursor + N;                    // E

  int nb16 = (N * 16 + 255) / 256;

  k_zero<<<(N + 255) / 256, 256, 0, stream>>>(cnt, N);
  k_count<<<(E + 255) / 256, 256, 0, stream>>>(dst, E, cnt);
  k_scan<<<1, 1024, 0, stream>>>(cnt, N, row_ptr, cursor,
                                 f2w, f2b, g1_wl, g1_bl, g1_wr, g2_wl, g2_wr, coef);
  k_scatter<<<(E + 255) / 256, 256, 0, stream>>>(src, dst, E, cursor, adj);
  k_mlp<<<(rows + 63) / 64, 256, 0, stream>>>(
      x, w_t, b_t, w_r, b_r, w_tp, b_tp, w_ssr, b_ssr,
      f1w, f1b, coef, F1v, F2v, N, rows);
  k_agg1<<<nb16, 256, 0, stream>>>(row_ptr, adj, F1v, F2v, W, V, N);
  k_agg2<<<nb16, 256, 0, stream>>>(row_ptr, adj, W, V, F2v, coef, g2_bl, out, N);
}